// Round 2
// 279.017 us; speedup vs baseline: 1.0017x; 1.0017x over previous
//
#include <hip/hip_runtime.h>
#include <math.h>

#define EPSF 1e-20f
#define Bv 4
#define Cv 32
#define Ov 32
#define Hv 256
#define Wv 256
#define HOv 128
#define WOv 128
#define NPIX (HOv * WOv)          // 16384
#define HALF_OUT (Bv * Ov * NPIX) // 2,097,152

__device__ __forceinline__ float softplus_f(float x) {
    return fmaxf(x, 0.0f) + log1pf(__expf(-fabsf(x)));
}
__device__ __forceinline__ float frcp(float x) {
    return __builtin_amdgcn_rcpf(x);
}

// ws layout (floats):
//  [0..31]     wp (softplus)
//  [32..319]   sw (c*9+k)
//  [320..1343] cw (o*32+c)
//  [1344] 1/(sum_sw+EPS)   [1345] 1/(sum_cw+EPS)
//  [2048 ...]  float2 buf[(b*32+c)*16384 + pix] = {cgx_sp*gx_sp, cgx_sp} (16.8MB)
#define WS_BUF_OFF 2048
#define WS_NEEDED (WS_BUF_OFF * 4 + (size_t)Bv * Cv * NPIX * 8)

__global__ void prep_kernel(const float* __restrict__ wp_raw,
                            const float* __restrict__ sw_raw,
                            const float* __restrict__ cw_raw,
                            float* __restrict__ ws) {
    __shared__ float red_sw[256];
    __shared__ float red_cw[256];
    const int t = threadIdx.x;
    float acc_sw = 0.f, acc_cw = 0.f;
    if (t < 32) ws[t] = softplus_f(wp_raw[t]);
    for (int i = t; i < 288; i += 256) {
        float v = softplus_f(sw_raw[i]);
        ws[32 + i] = v;
        acc_sw += v;
    }
    for (int i = t; i < 1024; i += 256) {
        float v = softplus_f(cw_raw[i]);
        ws[320 + i] = v;
        acc_cw += v;
    }
    red_sw[t] = acc_sw;
    red_cw[t] = acc_cw;
    __syncthreads();
    for (int st = 128; st > 0; st >>= 1) {
        if (t < st) { red_sw[t] += red_sw[t + st]; red_cw[t] += red_cw[t + st]; }
        __syncthreads();
    }
    if (t == 0) {
        ws[1344] = 1.0f / (red_sw[0] + EPSF);
        ws[1345] = 1.0f / (red_cw[0] + EPSF);
    }
}

// ================= K1: no-LDS, no-barrier, shuffle for left tap ==========
// One wave per output row slice: lane l computes pixels (ho, 2l) and (ho,
// 2l+1). It loads its own 3 input rows (h = 2ho-1 .. 2ho+1) as float4 per
// array (15 float4 loads, all independent) + 9 float2 sprod loads. Stage A
// is pointwise; the left tap (stage-A output at col 4l-1) comes from lane
// l-1 elem 3 via __shfl_up. Vertical re-reads hit L1/L2 (same/adjacent
// waves), not HBM.
//
// ROUND-N CHANGE: previous build allocated only 40 VGPRs — the scheduler
// sank all 24 loads next to their uses and serialized them (rocprof: 94 µs,
// HBM 21%, VALUBusy 13% == latency-bound). sched_barrier(0) after the load
// cluster pins every load BEFORE any compute, forcing the payload (~78
// VGPRs) live and giving each wave 24 loads in flight instead of ~2.
// __launch_bounds__(256,2) keeps the 256-VGPR cap so this fits w/o spill.
__global__ __launch_bounds__(256, 2)
void k1_spatial(const float* __restrict__ d,  const float* __restrict__ cd,
                const float* __restrict__ s,  const float* __restrict__ gx,
                const float* __restrict__ cgx, const float* __restrict__ sprod,
                const float* __restrict__ ws, float2* __restrict__ buf) {
    const int t  = threadIdx.x;
    const int l  = t & 63;            // lane
    const int q  = t >> 6;            // wave id 0..3
    const int ho = blockIdx.x * 4 + q;
    const int z  = blockIdx.y;        // b*32 + c
    const int c  = z & 31;

    const float wpc = ws[c];                  // wave-uniform -> scalar
    const float inv_wp1 = frcp(wpc + 1.0f);
    const float inv_sumsw = ws[1344];
    const float* sw_c = ws + 32 + c * 9;

    const int ibase = z * (Hv * Wv);
    const int h_top = 2 * ho - 1;
    const bool row0_ok = (h_top >= 0);        // only false for ho==0
    const int col = 4 * l;

    int gaddr[3];
    gaddr[0] = ibase + (row0_ok ? h_top : 0) * Wv + col;  // clamped-safe
    gaddr[1] = ibase + (h_top + 1) * Wv + col;
    gaddr[2] = ibase + (h_top + 2) * Wv + col;

    // ---- issue ALL loads up front (15 float4 + 9 float2, independent) ----
    float4 Dv[3], Cd[3], Sv[3], Gv[3], Cg[3];
#pragma unroll
    for (int r = 0; r < 3; ++r) {
        Dv[r] = *(const float4*)(d   + gaddr[r]);
        Cd[r] = *(const float4*)(cd  + gaddr[r]);
        Sv[r] = *(const float4*)(s   + gaddr[r]);
        Gv[r] = *(const float4*)(gx  + gaddr[r]);
        Cg[r] = *(const float4*)(cgx + gaddr[r]);
    }
    const int sp0 = (z * 9 * HOv + ho) * WOv + 2 * l;
    float2 sp[9];
#pragma unroll
    for (int k = 0; k < 9; ++k)
        sp[k] = *(const float2*)(sprod + sp0 + k * NPIX);

    // Pin the load cluster: nothing may be scheduled across this point, so
    // all 24 VMEM loads issue before the first compute instruction and stay
    // in flight together (MLP 24/wave instead of ~2/wave at 40 VGPR).
    __builtin_amdgcn_sched_barrier(0);

    // ---- per row: stage-A (pointwise) + shfl left tap + spatial taps ----
    float nom0 = 0.f, den0 = 0.f, nom1 = 0.f, den1 = 0.f;
#pragma unroll
    for (int r = 0; r < 3; ++r) {
        const bool vrow = (r > 0) || row0_ok;
        const float* Df = (const float*)&Dv[r];
        const float* CDf = (const float*)&Cd[r];
        const float* Sf = (const float*)&Sv[r];
        const float* Gf = (const float*)&Gv[r];
        const float* Cf = (const float*)&Cg[r];
        float gn[4], cn[4];
#pragma unroll
        for (int e = 0; e < 4; ++e) {
            const int w = col + e;
            const bool mL = (w != Wv - 1);     // pad_r zeros last col
            const bool mR = (w != 0);          // pad_l zeros first col
            const float dV = Df[e], cdV = CDf[e], sV = Sf[e];
            const float dL  = mL ? dV  : 0.f;
            const float cdL = mL ? cdV : 0.f;
            const float sL  = mL ? sV  : 0.f;
            const float dR  = mR ? dV  : 0.f;
            const float cdR = mR ? cdV : 0.f;
            const float sR  = mR ? sV  : 0.f;
            const float cgx_ds = sV * sL * sR * cdL * cdR;
            const float height = (cdL * dL + cdR * dR) * frcp(cdL + cdR + EPSF);
            const float gx_ds  = (dR - dL) * 0.5f * frcp(height + EPSF);
            const float a = wpc * Cf[e];
            const float g_ = (a * Gf[e] + cgx_ds * gx_ds) * frcp(a + cgx_ds + EPSF);
            const float c_ = (a + cgx_ds) * inv_wp1;
            gn[e] = vrow ? g_ : 0.f;
            cn[e] = vrow ? c_ : 0.f;
        }
        // left tap: stage-A output at col-1 = lane l-1's elem 3
        float ge = __shfl_up(gn[3], 1, 64);
        float ce = __shfl_up(cn[3], 1, 64);
        ge = l ? ge : 0.f;                     // w = -1 tap is zero
        ce = l ? ce : 0.f;
        const float sw0 = sw_c[3 * r + 0];
        const float sw1 = sw_c[3 * r + 1];
        const float sw2 = sw_c[3 * r + 2];
        float cp;
        // pixel wo0 = 2l : taps w = col-1, col, col+1
        cp = ce    * sp[3 * r + 0].x * sw0; den0 += cp; nom0 = fmaf(cp, ge,    nom0);
        cp = cn[0] * sp[3 * r + 1].x * sw1; den0 += cp; nom0 = fmaf(cp, gn[0], nom0);
        cp = cn[1] * sp[3 * r + 2].x * sw2; den0 += cp; nom0 = fmaf(cp, gn[1], nom0);
        // pixel wo1 = 2l+1 : taps w = col+1, col+2, col+3
        cp = cn[1] * sp[3 * r + 0].y * sw0; den1 += cp; nom1 = fmaf(cp, gn[1], nom1);
        cp = cn[2] * sp[3 * r + 1].y * sw1; den1 += cp; nom1 = fmaf(cp, gn[2], nom1);
        cp = cn[3] * sp[3 * r + 2].y * sw2; den1 += cp; nom1 = fmaf(cp, gn[3], nom1);
    }
    const float gx0 = nom0 * frcp(den0 + EPSF);
    const float cg0 = den0 * inv_sumsw;
    const float gx1 = nom1 * frcp(den1 + EPSF);
    const float cg1 = den1 * inv_sumsw;
    float4 ov = {cg0 * gx0, cg0, cg1 * gx1, cg1};
    *(float4*)(buf + (size_t)z * NPIX + ho * WOv + 2 * l) = ov;
}

// ================= K2: 32->32 channel mix (o split in 2 groups) ===========
__global__ __launch_bounds__(256)
void k2_channel(const float2* __restrict__ buf, const float* __restrict__ ws,
                const float* __restrict__ bias, float* __restrict__ out) {
    const int pg  = blockIdx.x * 256 + threadIdx.x;  // 0..65535
    const int b   = pg >> 14;
    const int pp  = pg & (NPIX - 1);
    const int grp = blockIdx.y;                      // 0..1
    const float* cw_t = ws + 320;
    const float inv_sumcw = ws[1345];

    float nom2[16], den2[16];
#pragma unroll
    for (int i = 0; i < 16; ++i) { nom2[i] = 0.f; den2[i] = 0.f; }

    const int cbase = b * Cv * NPIX + pp;
#pragma unroll
    for (int cc = 0; cc < Cv; ++cc) {
        const float2 v = buf[cbase + cc * NPIX];
#pragma unroll
        for (int oi = 0; oi < 16; ++oi) {
            const float w_ = cw_t[(grp * 16 + oi) * Cv + cc];  // uniform
            nom2[oi] = fmaf(v.x, w_, nom2[oi]);
            den2[oi] = fmaf(v.y, w_, den2[oi]);
        }
    }
#pragma unroll
    for (int oi = 0; oi < 16; ++oi) {
        const int o = grp * 16 + oi;
        const int p = (b * Ov + o) * NPIX + pp;
        const float dn = den2[oi];
        const float g  = nom2[oi] * frcp(dn + EPSF) + bias[o];
        out[p]            = g * 2.0f;
        out[HALF_OUT + p] = dn * inv_sumcw * 0.25f;
    }
}

// ================= fallback: fully fused (round-1) kernel =================
#define TH 4
#define TW 32
#define IH 9
#define IW 65
#define IWP 66
#define NTILE (IH * IW)

__global__ __launch_bounds__(128)
void main_kernel(const float* __restrict__ d,  const float* __restrict__ cd,
                 const float* __restrict__ s,  const float* __restrict__ gx,
                 const float* __restrict__ cgx, const float* __restrict__ sprod,
                 const float* __restrict__ bias, const float* __restrict__ ws,
                 float* __restrict__ out) {
    __shared__ float lgx[IH][IWP];
    __shared__ float lcgx[IH][IWP];
    const int t    = threadIdx.x;
    const int wo_l = t & 31;
    const int ho_l = t >> 5;
    const int wo0  = blockIdx.x * TW;
    const int ho0  = blockIdx.y * TH;
    const int b    = blockIdx.z;
    const int ho   = ho0 + ho_l;
    const int wo   = wo0 + wo_l;
    const float* sw_t = ws + 32;
    const float* cw_t = ws + 320;
    const float inv_sumsw = ws[1344];
    const float inv_sumcw = ws[1345];
    float nom2[Ov], den2[Ov];
#pragma unroll
    for (int o = 0; o < Ov; ++o) { nom2[o] = 0.f; den2[o] = 0.f; }
    const int h_base = 2 * ho0 - 1;
    const int w_base = 2 * wo0 - 1;
    for (int c = 0; c < Cv; ++c) {
        const float wpc = ws[c];
        const float inv_wp1 = frcp(wpc + 1.0f);
        const int ibase = (b * Cv + c) * (Hv * Wv);
        for (int idx = t; idx < NTILE; idx += 128) {
            const int r  = idx / IW;
            const int cc = idx - r * IW;
            const int h  = h_base + r;
            const int w  = w_base + cc;
            float gxn = 0.f, cgxn = 0.f;
            if ((unsigned)h < (unsigned)Hv && (unsigned)w < (unsigned)Wv) {
                const int p = ibase + h * Wv + w;
                const float dv = d[p], cdv = cd[p], sv = s[p];
                const float gxv = gx[p], cgxv = cgx[p];
                const bool mLb = (w != Wv - 1);
                const bool mRb = (w != 0);
                const float dL = mLb ? dv : 0.f, cdL = mLb ? cdv : 0.f, sL = mLb ? sv : 0.f;
                const float dR = mRb ? dv : 0.f, cdR = mRb ? cdv : 0.f, sR = mRb ? sv : 0.f;
                const float cgx_ds = sv * sL * sR * cdL * cdR;
                const float height = (cdL * dL + cdR * dR) * frcp(cdL + cdR + EPSF);
                const float gx_ds  = (dR - dL) * 0.5f * frcp(height + EPSF);
                const float a = wpc * cgxv;
                gxn  = (a * gxv + cgx_ds * gx_ds) * frcp(a + cgx_ds + EPSF);
                cgxn = (a + cgx_ds) * inv_wp1;
            }
            lgx[r][cc]  = gxn;
            lcgx[r][cc] = cgxn;
        }
        __syncthreads();
        const int spb = ((b * Cv + c) * 9 * HOv + ho) * WOv + wo;
        float nom = 0.f, den = 0.f;
#pragma unroll
        for (int k = 0; k < 9; ++k) {
            const int ki = k / 3;
            const int kj = k - ki * 3;
            const float gxr  = lgx[2 * ho_l + ki][2 * wo_l + kj];
            const float cgxr = lcgx[2 * ho_l + ki][2 * wo_l + kj];
            const float spv  = sprod[spb + k * NPIX];
            const float cp   = cgxr * spv * sw_t[c * 9 + k];
            den += cp;
            nom = fmaf(cp, gxr, nom);
        }
        const float gx_sp  = nom * frcp(den + EPSF);
        const float cgx_sp = den * inv_sumsw;
        const float t1 = cgx_sp * gx_sp;
#pragma unroll
        for (int o = 0; o < Ov; ++o) {
            const float w_ = cw_t[o * Cv + c];
            nom2[o] = fmaf(t1, w_, nom2[o]);
            den2[o] = fmaf(cgx_sp, w_, den2[o]);
        }
        __syncthreads();
    }
#pragma unroll
    for (int o = 0; o < Ov; ++o) {
        const int p = ((b * Ov + o) * HOv + ho) * WOv + wo;
        const float dn = den2[o];
        const float g  = nom2[o] * frcp(dn + EPSF) + bias[o];
        out[p]            = g * 2.0f;
        out[HALF_OUT + p] = dn * inv_sumcw * 0.25f;
    }
}

extern "C" void kernel_launch(void* const* d_in, const int* in_sizes, int n_in,
                              void* d_out, int out_size, void* d_ws, size_t ws_size,
                              hipStream_t stream) {
    const float* d_ptr    = (const float*)d_in[0];
    const float* cd_ptr   = (const float*)d_in[1];
    const float* s_ptr    = (const float*)d_in[2];
    // d_in[3] = cs : unused by the reference
    const float* gx_ptr   = (const float*)d_in[4];
    const float* cgx_ptr  = (const float*)d_in[5];
    const float* sp_ptr   = (const float*)d_in[6];
    const float* wp_ptr   = (const float*)d_in[7];
    const float* sw_ptr   = (const float*)d_in[8];
    const float* cw_ptr   = (const float*)d_in[9];
    const float* bias_ptr = (const float*)d_in[10];
    float* out = (float*)d_out;
    float* ws  = (float*)d_ws;

    prep_kernel<<<1, 256, 0, stream>>>(wp_ptr, sw_ptr, cw_ptr, ws);

    if (ws_size >= WS_NEEDED) {
        float2* buf = (float2*)(ws + WS_BUF_OFF);
        dim3 g1(HOv / 4, Bv * Cv, 1);            // 32 x 128 = 4096 blocks
        k1_spatial<<<g1, 256, 0, stream>>>(d_ptr, cd_ptr, s_ptr, gx_ptr, cgx_ptr,
                                           sp_ptr, ws, buf);
        dim3 g2((Bv * NPIX) / 256, 2, 1);        // 256 x 2 blocks
        k2_channel<<<g2, 256, 0, stream>>>(buf, ws, bias_ptr, out);
    } else {
        dim3 grid(WOv / TW, HOv / TH, Bv);
        main_kernel<<<grid, 128, 0, stream>>>(d_ptr, cd_ptr, s_ptr, gx_ptr, cgx_ptr,
                                              sp_ptr, bias_ptr, ws, out);
    }
}

// Round 3
// 278.079 us; speedup vs baseline: 1.0051x; 1.0034x over previous
//
#include <hip/hip_runtime.h>
#include <math.h>

#define EPSF 1e-20f
#define Bv 4
#define Cv 32
#define Ov 32
#define Hv 256
#define Wv 256
#define HOv 128
#define WOv 128
#define NPIX (HOv * WOv)          // 16384
#define HALF_OUT (Bv * Ov * NPIX) // 2,097,152

__device__ __forceinline__ float softplus_f(float x) {
    return fmaxf(x, 0.0f) + log1pf(__expf(-fabsf(x)));
}
__device__ __forceinline__ float frcp(float x) {
    return __builtin_amdgcn_rcpf(x);
}

// Force a loaded value to be materialized in a VGPR at this program point.
// Unlike sched_barrier (a hint the backend ignored: VGPR stayed 44), this is
// a DATA dependence: the volatile asm reads+writes the value, so the load
// cannot sink below it and RA must keep the payload live.
#define PIN4(v4) asm volatile("" : "+v"((v4).x), "+v"((v4).y), "+v"((v4).z), "+v"((v4).w))
#define PIN2(v2) asm volatile("" : "+v"((v2).x), "+v"((v2).y))

// ws layout (floats):
//  [0..31]     wp (softplus)
//  [32..319]   sw (c*9+k)
//  [320..1343] cw (o*32+c)
//  [1344] 1/(sum_sw+EPS)   [1345] 1/(sum_cw+EPS)
//  [2048 ...]  float2 buf[(b*32+c)*16384 + pix] = {cgx_sp*gx_sp, cgx_sp} (16.8MB)
#define WS_BUF_OFF 2048
#define WS_NEEDED (WS_BUF_OFF * 4 + (size_t)Bv * Cv * NPIX * 8)

__global__ void prep_kernel(const float* __restrict__ wp_raw,
                            const float* __restrict__ sw_raw,
                            const float* __restrict__ cw_raw,
                            float* __restrict__ ws) {
    __shared__ float red_sw[256];
    __shared__ float red_cw[256];
    const int t = threadIdx.x;
    float acc_sw = 0.f, acc_cw = 0.f;
    if (t < 32) ws[t] = softplus_f(wp_raw[t]);
    for (int i = t; i < 288; i += 256) {
        float v = softplus_f(sw_raw[i]);
        ws[32 + i] = v;
        acc_sw += v;
    }
    for (int i = t; i < 1024; i += 256) {
        float v = softplus_f(cw_raw[i]);
        ws[320 + i] = v;
        acc_cw += v;
    }
    red_sw[t] = acc_sw;
    red_cw[t] = acc_cw;
    __syncthreads();
    for (int st = 128; st > 0; st >>= 1) {
        if (t < st) { red_sw[t] += red_sw[t + st]; red_cw[t] += red_cw[t + st]; }
        __syncthreads();
    }
    if (t == 0) {
        ws[1344] = 1.0f / (red_sw[0] + EPSF);
        ws[1345] = 1.0f / (red_cw[0] + EPSF);
    }
}

// ================= K1: no-LDS, no-barrier, shuffle for left tap ==========
// One wave per output row slice: lane l computes pixels (ho, 2l) and (ho,
// 2l+1). It loads its own 3 input rows (h = 2ho-1 .. 2ho+1) as float4 per
// array (15 float4 loads, all independent) + 9 float2 sprod loads. Stage A
// is pointwise; the left tap (stage-A output at col 4l-1) comes from lane
// l-1 elem 3 via __shfl_up. Vertical re-reads hit L1/L2/LLC, not HBM.
//
// ROUND-2 EVIDENCE: sched_barrier(0) left VGPR at 44 => loads still
// serialized (MLP~1, ~50k cyc/wave, VALUBusy 13%, HBM 21%). ROUND-3 CHANGE:
// asm-operand PINs after the load cluster create hard data dependences —
// all 24 VMEM ops must issue before the pin block, forcing ~78 payload
// VGPRs live and MLP=24/wave. __launch_bounds__(256,2) keeps a 256-VGPR
// cap so ~110 VGPR fits with no spill (4 waves/SIMD).
__global__ __launch_bounds__(256, 2)
void k1_spatial(const float* __restrict__ d,  const float* __restrict__ cd,
                const float* __restrict__ s,  const float* __restrict__ gx,
                const float* __restrict__ cgx, const float* __restrict__ sprod,
                const float* __restrict__ ws, float2* __restrict__ buf) {
    const int t  = threadIdx.x;
    const int l  = t & 63;            // lane
    const int q  = t >> 6;            // wave id 0..3
    const int ho = blockIdx.x * 4 + q;
    const int z  = blockIdx.y;        // b*32 + c
    const int c  = z & 31;

    const float wpc = ws[c];                  // wave-uniform -> scalar
    const float inv_wp1 = frcp(wpc + 1.0f);
    const float inv_sumsw = ws[1344];
    const float* sw_c = ws + 32 + c * 9;

    const int ibase = z * (Hv * Wv);
    const int h_top = 2 * ho - 1;
    const bool row0_ok = (h_top >= 0);        // only false for ho==0
    const int col = 4 * l;

    int gaddr[3];
    gaddr[0] = ibase + (row0_ok ? h_top : 0) * Wv + col;  // clamped-safe
    gaddr[1] = ibase + (h_top + 1) * Wv + col;
    gaddr[2] = ibase + (h_top + 2) * Wv + col;

    // ---- issue ALL loads up front (15 float4 + 9 float2, independent) ----
    float4 Dv[3], Cd[3], Sv[3], Gv[3], Cg[3];
#pragma unroll
    for (int r = 0; r < 3; ++r) {
        Dv[r] = *(const float4*)(d   + gaddr[r]);
        Cd[r] = *(const float4*)(cd  + gaddr[r]);
        Sv[r] = *(const float4*)(s   + gaddr[r]);
        Gv[r] = *(const float4*)(gx  + gaddr[r]);
        Cg[r] = *(const float4*)(cgx + gaddr[r]);
    }
    const int sp0 = (z * 9 * HOv + ho) * WOv + 2 * l;
    float2 sp[9];
#pragma unroll
    for (int k = 0; k < 9; ++k)
        sp[k] = *(const float2*)(sprod + sp0 + k * NPIX);

    // ---- PIN: hard data-dependence fence; all 24 loads stay clustered ----
#pragma unroll
    for (int r = 0; r < 3; ++r) {
        PIN4(Dv[r]); PIN4(Cd[r]); PIN4(Sv[r]); PIN4(Gv[r]); PIN4(Cg[r]);
    }
#pragma unroll
    for (int k = 0; k < 9; ++k) PIN2(sp[k]);

    // ---- per row: stage-A (pointwise) + shfl left tap + spatial taps ----
    float nom0 = 0.f, den0 = 0.f, nom1 = 0.f, den1 = 0.f;
#pragma unroll
    for (int r = 0; r < 3; ++r) {
        const bool vrow = (r > 0) || row0_ok;
        const float* Df = (const float*)&Dv[r];
        const float* CDf = (const float*)&Cd[r];
        const float* Sf = (const float*)&Sv[r];
        const float* Gf = (const float*)&Gv[r];
        const float* Cf = (const float*)&Cg[r];
        float gn[4], cn[4];
#pragma unroll
        for (int e = 0; e < 4; ++e) {
            const int w = col + e;
            const bool mL = (w != Wv - 1);     // pad_r zeros last col
            const bool mR = (w != 0);          // pad_l zeros first col
            const float dV = Df[e], cdV = CDf[e], sV = Sf[e];
            const float dL  = mL ? dV  : 0.f;
            const float cdL = mL ? cdV : 0.f;
            const float sL  = mL ? sV  : 0.f;
            const float dR  = mR ? dV  : 0.f;
            const float cdR = mR ? cdV : 0.f;
            const float sR  = mR ? sV  : 0.f;
            const float cgx_ds = sV * sL * sR * cdL * cdR;
            const float height = (cdL * dL + cdR * dR) * frcp(cdL + cdR + EPSF);
            const float gx_ds  = (dR - dL) * 0.5f * frcp(height + EPSF);
            const float a = wpc * Cf[e];
            const float g_ = (a * Gf[e] + cgx_ds * gx_ds) * frcp(a + cgx_ds + EPSF);
            const float c_ = (a + cgx_ds) * inv_wp1;
            gn[e] = vrow ? g_ : 0.f;
            cn[e] = vrow ? c_ : 0.f;
        }
        // left tap: stage-A output at col-1 = lane l-1's elem 3
        float ge = __shfl_up(gn[3], 1, 64);
        float ce = __shfl_up(cn[3], 1, 64);
        ge = l ? ge : 0.f;                     // w = -1 tap is zero
        ce = l ? ce : 0.f;
        const float sw0 = sw_c[3 * r + 0];
        const float sw1 = sw_c[3 * r + 1];
        const float sw2 = sw_c[3 * r + 2];
        float cp;
        // pixel wo0 = 2l : taps w = col-1, col, col+1
        cp = ce    * sp[3 * r + 0].x * sw0; den0 += cp; nom0 = fmaf(cp, ge,    nom0);
        cp = cn[0] * sp[3 * r + 1].x * sw1; den0 += cp; nom0 = fmaf(cp, gn[0], nom0);
        cp = cn[1] * sp[3 * r + 2].x * sw2; den0 += cp; nom0 = fmaf(cp, gn[1], nom0);
        // pixel wo1 = 2l+1 : taps w = col+1, col+2, col+3
        cp = cn[1] * sp[3 * r + 0].y * sw0; den1 += cp; nom1 = fmaf(cp, gn[1], nom1);
        cp = cn[2] * sp[3 * r + 1].y * sw1; den1 += cp; nom1 = fmaf(cp, gn[2], nom1);
        cp = cn[3] * sp[3 * r + 2].y * sw2; den1 += cp; nom1 = fmaf(cp, gn[3], nom1);
    }
    const float gx0 = nom0 * frcp(den0 + EPSF);
    const float cg0 = den0 * inv_sumsw;
    const float gx1 = nom1 * frcp(den1 + EPSF);
    const float cg1 = den1 * inv_sumsw;
    float4 ov = {cg0 * gx0, cg0, cg1 * gx1, cg1};
    *(float4*)(buf + (size_t)z * NPIX + ho * WOv + 2 * l) = ov;
}

// ================= K2: 32->32 channel mix (o split in 2 groups) ===========
// ROUND-3 CHANGE: same MLP disease as k1 — 32 independent float2 loads were
// interleaved with their FMA clumps (one in flight at a time). Preload all
// 32 into a pinned register array (64 payload VGPRs), then run the FMA
// loops. launch_bounds(256,2) lifts the VGPR cap so RA doesn't re-serialize.
__global__ __launch_bounds__(256, 2)
void k2_channel(const float2* __restrict__ buf, const float* __restrict__ ws,
                const float* __restrict__ bias, float* __restrict__ out) {
    const int pg  = blockIdx.x * 256 + threadIdx.x;  // 0..65535
    const int b   = pg >> 14;
    const int pp  = pg & (NPIX - 1);
    const int grp = blockIdx.y;                      // 0..1
    const float* cw_t = ws + 320;
    const float inv_sumcw = ws[1345];

    const int cbase = b * Cv * NPIX + pp;

    // ---- issue all 32 loads up front, then pin ----
    float2 v[Cv];
#pragma unroll
    for (int cc = 0; cc < Cv; ++cc)
        v[cc] = buf[cbase + cc * NPIX];
#pragma unroll
    for (int cc = 0; cc < Cv; ++cc) PIN2(v[cc]);

    float nom2[16], den2[16];
#pragma unroll
    for (int i = 0; i < 16; ++i) { nom2[i] = 0.f; den2[i] = 0.f; }

#pragma unroll
    for (int cc = 0; cc < Cv; ++cc) {
#pragma unroll
        for (int oi = 0; oi < 16; ++oi) {
            const float w_ = cw_t[(grp * 16 + oi) * Cv + cc];  // uniform
            nom2[oi] = fmaf(v[cc].x, w_, nom2[oi]);
            den2[oi] = fmaf(v[cc].y, w_, den2[oi]);
        }
    }
#pragma unroll
    for (int oi = 0; oi < 16; ++oi) {
        const int o = grp * 16 + oi;
        const int p = (b * Ov + o) * NPIX + pp;
        const float dn = den2[oi];
        const float g  = nom2[oi] * frcp(dn + EPSF) + bias[o];
        out[p]            = g * 2.0f;
        out[HALF_OUT + p] = dn * inv_sumcw * 0.25f;
    }
}

// ================= fallback: fully fused (round-1) kernel =================
#define TH 4
#define TW 32
#define IH 9
#define IW 65
#define IWP 66
#define NTILE (IH * IW)

__global__ __launch_bounds__(128)
void main_kernel(const float* __restrict__ d,  const float* __restrict__ cd,
                 const float* __restrict__ s,  const float* __restrict__ gx,
                 const float* __restrict__ cgx, const float* __restrict__ sprod,
                 const float* __restrict__ bias, const float* __restrict__ ws,
                 float* __restrict__ out) {
    __shared__ float lgx[IH][IWP];
    __shared__ float lcgx[IH][IWP];
    const int t    = threadIdx.x;
    const int wo_l = t & 31;
    const int ho_l = t >> 5;
    const int wo0  = blockIdx.x * TW;
    const int ho0  = blockIdx.y * TH;
    const int b    = blockIdx.z;
    const int ho   = ho0 + ho_l;
    const int wo   = wo0 + wo_l;
    const float* sw_t = ws + 32;
    const float* cw_t = ws + 320;
    const float inv_sumsw = ws[1344];
    const float inv_sumcw = ws[1345];
    float nom2[Ov], den2[Ov];
#pragma unroll
    for (int o = 0; o < Ov; ++o) { nom2[o] = 0.f; den2[o] = 0.f; }
    const int h_base = 2 * ho0 - 1;
    const int w_base = 2 * wo0 - 1;
    for (int c = 0; c < Cv; ++c) {
        const float wpc = ws[c];
        const float inv_wp1 = frcp(wpc + 1.0f);
        const int ibase = (b * Cv + c) * (Hv * Wv);
        for (int idx = t; idx < NTILE; idx += 128) {
            const int r  = idx / IW;
            const int cc = idx - r * IW;
            const int h  = h_base + r;
            const int w  = w_base + cc;
            float gxn = 0.f, cgxn = 0.f;
            if ((unsigned)h < (unsigned)Hv && (unsigned)w < (unsigned)Wv) {
                const int p = ibase + h * Wv + w;
                const float dv = d[p], cdv = cd[p], sv = s[p];
                const float gxv = gx[p], cgxv = cgx[p];
                const bool mLb = (w != Wv - 1);
                const bool mRb = (w != 0);
                const float dL = mLb ? dv : 0.f, cdL = mLb ? cdv : 0.f, sL = mLb ? sv : 0.f;
                const float dR = mRb ? dv : 0.f, cdR = mRb ? cdv : 0.f, sR = mRb ? sv : 0.f;
                const float cgx_ds = sv * sL * sR * cdL * cdR;
                const float height = (cdL * dL + cdR * dR) * frcp(cdL + cdR + EPSF);
                const float gx_ds  = (dR - dL) * 0.5f * frcp(height + EPSF);
                const float a = wpc * cgxv;
                gxn  = (a * gxv + cgx_ds * gx_ds) * frcp(a + cgx_ds + EPSF);
                cgxn = (a + cgx_ds) * inv_wp1;
            }
            lgx[r][cc]  = gxn;
            lcgx[r][cc] = cgxn;
        }
        __syncthreads();
        const int spb = ((b * Cv + c) * 9 * HOv + ho) * WOv + wo;
        float nom = 0.f, den = 0.f;
#pragma unroll
        for (int k = 0; k < 9; ++k) {
            const int ki = k / 3;
            const int kj = k - ki * 3;
            const float gxr  = lgx[2 * ho_l + ki][2 * wo_l + kj];
            const float cgxr = lcgx[2 * ho_l + ki][2 * wo_l + kj];
            const float spv  = sprod[spb + k * NPIX];
            const float cp   = cgxr * spv * sw_t[c * 9 + k];
            den += cp;
            nom = fmaf(cp, gxr, nom);
        }
        const float gx_sp  = nom * frcp(den + EPSF);
        const float cgx_sp = den * inv_sumsw;
        const float t1 = cgx_sp * gx_sp;
#pragma unroll
        for (int o = 0; o < Ov; ++o) {
            const float w_ = cw_t[o * Cv + c];
            nom2[o] = fmaf(t1, w_, nom2[o]);
            den2[o] = fmaf(cgx_sp, w_, den2[o]);
        }
        __syncthreads();
    }
#pragma unroll
    for (int o = 0; o < Ov; ++o) {
        const int p = ((b * Ov + o) * HOv + ho) * WOv + wo;
        const float dn = den2[o];
        const float g  = nom2[o] * frcp(dn + EPSF) + bias[o];
        out[p]            = g * 2.0f;
        out[HALF_OUT + p] = dn * inv_sumcw * 0.25f;
    }
}

extern "C" void kernel_launch(void* const* d_in, const int* in_sizes, int n_in,
                              void* d_out, int out_size, void* d_ws, size_t ws_size,
                              hipStream_t stream) {
    const float* d_ptr    = (const float*)d_in[0];
    const float* cd_ptr   = (const float*)d_in[1];
    const float* s_ptr    = (const float*)d_in[2];
    // d_in[3] = cs : unused by the reference
    const float* gx_ptr   = (const float*)d_in[4];
    const float* cgx_ptr  = (const float*)d_in[5];
    const float* sp_ptr   = (const float*)d_in[6];
    const float* wp_ptr   = (const float*)d_in[7];
    const float* sw_ptr   = (const float*)d_in[8];
    const float* cw_ptr   = (const float*)d_in[9];
    const float* bias_ptr = (const float*)d_in[10];
    float* out = (float*)d_out;
    float* ws  = (float*)d_ws;

    prep_kernel<<<1, 256, 0, stream>>>(wp_ptr, sw_ptr, cw_ptr, ws);

    if (ws_size >= WS_NEEDED) {
        float2* buf = (float2*)(ws + WS_BUF_OFF);
        dim3 g1(HOv / 4, Bv * Cv, 1);            // 32 x 128 = 4096 blocks
        k1_spatial<<<g1, 256, 0, stream>>>(d_ptr, cd_ptr, s_ptr, gx_ptr, cgx_ptr,
                                           sp_ptr, ws, buf);
        dim3 g2((Bv * NPIX) / 256, 2, 1);        // 256 x 2 blocks
        k2_channel<<<g2, 256, 0, stream>>>(buf, ws, bias_ptr, out);
    } else {
        dim3 grid(WOv / TW, HOv / TH, Bv);
        main_kernel<<<grid, 128, 0, stream>>>(d_ptr, cd_ptr, s_ptr, gx_ptr, cgx_ptr,
                                              sp_ptr, bias_ptr, ws, out);
    }
}

// Round 4
// 276.709 us; speedup vs baseline: 1.0100x; 1.0050x over previous
//
#include <hip/hip_runtime.h>
#include <math.h>

#define EPSF 1e-20f
#define Bv 4
#define Cv 32
#define Ov 32
#define Hv 256
#define Wv 256
#define HOv 128
#define WOv 128
#define NPIX (HOv * WOv)          // 16384
#define HALF_OUT (Bv * Ov * NPIX) // 2,097,152

__device__ __forceinline__ float softplus_f(float x) {
    return fmaxf(x, 0.0f) + log1pf(__expf(-fabsf(x)));
}
__device__ __forceinline__ float frcp(float x) {
    return __builtin_amdgcn_rcpf(x);
}

// Opaque volatile asm loads: the ONLY schedule-proof way to cluster VMEM.
// Volatile asms are strictly ordered among themselves -> all loads issue
// before the single s_waitcnt. (sched_barrier / per-value pins both failed:
// the backend kept sinking visible loads to their first use; VGPR stayed
// 44-52 and MLP~1 across rounds 0-3.)
__device__ __forceinline__ float4 gload4(const float* p) {
    float4 r;
    asm volatile("global_load_dwordx4 %0, %1, off" : "=v"(r) : "v"(p));
    return r;
}
__device__ __forceinline__ float2 gload2(const float* p) {
    float2 r;
    asm volatile("global_load_dwordx2 %0, %1, off" : "=v"(r) : "v"(p));
    return r;
}
// Drain + fence. Rule #18: hipcc can hoist register-only consumers past an
// inline-asm waitcnt ("memory" doesn't order non-memory ops) — the
// sched_barrier(0) immediately after is the required fence.
__device__ __forceinline__ void vm_drain() {
    asm volatile("s_waitcnt vmcnt(0)" ::: "memory");
    __builtin_amdgcn_sched_barrier(0);
}

// ws layout (floats):
//  [0..31]     wp (softplus)
//  [32..319]   sw (c*9+k)
//  [320..1343] cw (o*32+c)
//  [1344] 1/(sum_sw+EPS)   [1345] 1/(sum_cw+EPS)
//  [2048 ...]  float2 buf[(b*32+c)*16384 + pix] = {cgx_sp*gx_sp, cgx_sp} (16.8MB)
#define WS_BUF_OFF 2048
#define WS_NEEDED (WS_BUF_OFF * 4 + (size_t)Bv * Cv * NPIX * 8)

__global__ void prep_kernel(const float* __restrict__ wp_raw,
                            const float* __restrict__ sw_raw,
                            const float* __restrict__ cw_raw,
                            float* __restrict__ ws) {
    __shared__ float red_sw[256];
    __shared__ float red_cw[256];
    const int t = threadIdx.x;
    float acc_sw = 0.f, acc_cw = 0.f;
    if (t < 32) ws[t] = softplus_f(wp_raw[t]);
    for (int i = t; i < 288; i += 256) {
        float v = softplus_f(sw_raw[i]);
        ws[32 + i] = v;
        acc_sw += v;
    }
    for (int i = t; i < 1024; i += 256) {
        float v = softplus_f(cw_raw[i]);
        ws[320 + i] = v;
        acc_cw += v;
    }
    red_sw[t] = acc_sw;
    red_cw[t] = acc_cw;
    __syncthreads();
    for (int st = 128; st > 0; st >>= 1) {
        if (t < st) { red_sw[t] += red_sw[t + st]; red_cw[t] += red_cw[t + st]; }
        __syncthreads();
    }
    if (t == 0) {
        ws[1344] = 1.0f / (red_sw[0] + EPSF);
        ws[1345] = 1.0f / (red_cw[0] + EPSF);
    }
}

// ================= K1: no-LDS, no-barrier, shuffle for left tap ==========
// One wave per output row slice: lane l computes pixels (ho, 2l) and (ho,
// 2l+1). 15 float4 + 9 float2 loads per thread, all independent, issued as
// ONE opaque asm cluster -> single vmcnt drain -> compute. Left tap via
// __shfl_up from lane l-1. Vertical re-reads hit L1/L2/LLC, not HBM.
__global__ __launch_bounds__(256, 2)
void k1_spatial(const float* __restrict__ d,  const float* __restrict__ cd,
                const float* __restrict__ s,  const float* __restrict__ gx,
                const float* __restrict__ cgx, const float* __restrict__ sprod,
                const float* __restrict__ ws, float2* __restrict__ buf) {
    const int t  = threadIdx.x;
    const int l  = t & 63;            // lane
    const int q  = t >> 6;            // wave id 0..3
    const int ho = blockIdx.x * 4 + q;
    const int z  = blockIdx.y;        // b*32 + c
    const int c  = z & 31;

    const float wpc = ws[c];                  // wave-uniform -> scalar
    const float inv_wp1 = frcp(wpc + 1.0f);
    const float inv_sumsw = ws[1344];
    const float* sw_c = ws + 32 + c * 9;

    const int ibase = z * (Hv * Wv);
    const int h_top = 2 * ho - 1;
    const bool row0_ok = (h_top >= 0);        // only false for ho==0
    const int col = 4 * l;

    int gaddr[3];
    gaddr[0] = ibase + (row0_ok ? h_top : 0) * Wv + col;  // clamped-safe
    gaddr[1] = ibase + (h_top + 1) * Wv + col;
    gaddr[2] = ibase + (h_top + 2) * Wv + col;

    // ---- opaque load cluster: 15 dwordx4 + 9 dwordx2, strictly ordered ----
    float4 Dv[3], Cd[3], Sv[3], Gv[3], Cg[3];
#pragma unroll
    for (int r = 0; r < 3; ++r) {
        Dv[r] = gload4(d   + gaddr[r]);
        Cd[r] = gload4(cd  + gaddr[r]);
        Sv[r] = gload4(s   + gaddr[r]);
        Gv[r] = gload4(gx  + gaddr[r]);
        Cg[r] = gload4(cgx + gaddr[r]);
    }
    const int sp0 = (z * 9 * HOv + ho) * WOv + 2 * l;
    float2 sp[9];
#pragma unroll
    for (int k = 0; k < 9; ++k)
        sp[k] = gload2(sprod + sp0 + k * NPIX);

    vm_drain();   // ONE waitcnt for all 24 loads; fence against hoisting

    // ---- per row: stage-A (pointwise) + shfl left tap + spatial taps ----
    float nom0 = 0.f, den0 = 0.f, nom1 = 0.f, den1 = 0.f;
#pragma unroll
    for (int r = 0; r < 3; ++r) {
        const bool vrow = (r > 0) || row0_ok;
        const float* Df = (const float*)&Dv[r];
        const float* CDf = (const float*)&Cd[r];
        const float* Sf = (const float*)&Sv[r];
        const float* Gf = (const float*)&Gv[r];
        const float* Cf = (const float*)&Cg[r];
        float gn[4], cn[4];
#pragma unroll
        for (int e = 0; e < 4; ++e) {
            const int w = col + e;
            const bool mL = (w != Wv - 1);     // pad_r zeros last col
            const bool mR = (w != 0);          // pad_l zeros first col
            const float dV = Df[e], cdV = CDf[e], sV = Sf[e];
            const float dL  = mL ? dV  : 0.f;
            const float cdL = mL ? cdV : 0.f;
            const float sL  = mL ? sV  : 0.f;
            const float dR  = mR ? dV  : 0.f;
            const float cdR = mR ? cdV : 0.f;
            const float sR  = mR ? sV  : 0.f;
            const float cgx_ds = sV * sL * sR * cdL * cdR;
            const float height = (cdL * dL + cdR * dR) * frcp(cdL + cdR + EPSF);
            const float gx_ds  = (dR - dL) * 0.5f * frcp(height + EPSF);
            const float a = wpc * Cf[e];
            const float g_ = (a * Gf[e] + cgx_ds * gx_ds) * frcp(a + cgx_ds + EPSF);
            const float c_ = (a + cgx_ds) * inv_wp1;
            gn[e] = vrow ? g_ : 0.f;
            cn[e] = vrow ? c_ : 0.f;
        }
        // left tap: stage-A output at col-1 = lane l-1's elem 3
        float ge = __shfl_up(gn[3], 1, 64);
        float ce = __shfl_up(cn[3], 1, 64);
        ge = l ? ge : 0.f;                     // w = -1 tap is zero
        ce = l ? ce : 0.f;
        const float sw0 = sw_c[3 * r + 0];
        const float sw1 = sw_c[3 * r + 1];
        const float sw2 = sw_c[3 * r + 2];
        float cp;
        // pixel wo0 = 2l : taps w = col-1, col, col+1
        cp = ce    * sp[3 * r + 0].x * sw0; den0 += cp; nom0 = fmaf(cp, ge,    nom0);
        cp = cn[0] * sp[3 * r + 1].x * sw1; den0 += cp; nom0 = fmaf(cp, gn[0], nom0);
        cp = cn[1] * sp[3 * r + 2].x * sw2; den0 += cp; nom0 = fmaf(cp, gn[1], nom0);
        // pixel wo1 = 2l+1 : taps w = col+1, col+2, col+3
        cp = cn[1] * sp[3 * r + 0].y * sw0; den1 += cp; nom1 = fmaf(cp, gn[1], nom1);
        cp = cn[2] * sp[3 * r + 1].y * sw1; den1 += cp; nom1 = fmaf(cp, gn[2], nom1);
        cp = cn[3] * sp[3 * r + 2].y * sw2; den1 += cp; nom1 = fmaf(cp, gn[3], nom1);
    }
    const float gx0 = nom0 * frcp(den0 + EPSF);
    const float cg0 = den0 * inv_sumsw;
    const float gx1 = nom1 * frcp(den1 + EPSF);
    const float cg1 = den1 * inv_sumsw;
    float4 ov = {cg0 * gx0, cg0, cg1 * gx1, cg1};
    *(float4*)(buf + (size_t)z * NPIX + ho * WOv + 2 * l) = ov;
}

// ================= K2: 32->32 channel mix (o split in 2 groups) ===========
// Same opaque-cluster treatment: 32 independent dwordx2 at 128KB stride,
// one drain, then the FMA loops (64 payload VGPRs forced live).
__global__ __launch_bounds__(256, 2)
void k2_channel(const float2* __restrict__ buf, const float* __restrict__ ws,
                const float* __restrict__ bias, float* __restrict__ out) {
    const int pg  = blockIdx.x * 256 + threadIdx.x;  // 0..65535
    const int b   = pg >> 14;
    const int pp  = pg & (NPIX - 1);
    const int grp = blockIdx.y;                      // 0..1
    const float* cw_t = ws + 320;
    const float inv_sumcw = ws[1345];

    const int cbase = b * Cv * NPIX + pp;

    float2 v[Cv];
#pragma unroll
    for (int cc = 0; cc < Cv; ++cc)
        v[cc] = gload2((const float*)(buf + cbase + cc * NPIX));

    vm_drain();

    float nom2[16], den2[16];
#pragma unroll
    for (int i = 0; i < 16; ++i) { nom2[i] = 0.f; den2[i] = 0.f; }

#pragma unroll
    for (int cc = 0; cc < Cv; ++cc) {
#pragma unroll
        for (int oi = 0; oi < 16; ++oi) {
            const float w_ = cw_t[(grp * 16 + oi) * Cv + cc];  // uniform
            nom2[oi] = fmaf(v[cc].x, w_, nom2[oi]);
            den2[oi] = fmaf(v[cc].y, w_, den2[oi]);
        }
    }
#pragma unroll
    for (int oi = 0; oi < 16; ++oi) {
        const int o = grp * 16 + oi;
        const int p = (b * Ov + o) * NPIX + pp;
        const float dn = den2[oi];
        const float g  = nom2[oi] * frcp(dn + EPSF) + bias[o];
        out[p]            = g * 2.0f;
        out[HALF_OUT + p] = dn * inv_sumcw * 0.25f;
    }
}

// ================= fallback: fully fused (round-1) kernel =================
#define TH 4
#define TW 32
#define IH 9
#define IW 65
#define IWP 66
#define NTILE (IH * IW)

__global__ __launch_bounds__(128)
void main_kernel(const float* __restrict__ d,  const float* __restrict__ cd,
                 const float* __restrict__ s,  const float* __restrict__ gx,
                 const float* __restrict__ cgx, const float* __restrict__ sprod,
                 const float* __restrict__ bias, const float* __restrict__ ws,
                 float* __restrict__ out) {
    __shared__ float lgx[IH][IWP];
    __shared__ float lcgx[IH][IWP];
    const int t    = threadIdx.x;
    const int wo_l = t & 31;
    const int ho_l = t >> 5;
    const int wo0  = blockIdx.x * TW;
    const int ho0  = blockIdx.y * TH;
    const int b    = blockIdx.z;
    const int ho   = ho0 + ho_l;
    const int wo   = wo0 + wo_l;
    const float* sw_t = ws + 32;
    const float* cw_t = ws + 320;
    const float inv_sumsw = ws[1344];
    const float inv_sumcw = ws[1345];
    float nom2[Ov], den2[Ov];
#pragma unroll
    for (int o = 0; o < Ov; ++o) { nom2[o] = 0.f; den2[o] = 0.f; }
    const int h_base = 2 * ho0 - 1;
    const int w_base = 2 * wo0 - 1;
    for (int c = 0; c < Cv; ++c) {
        const float wpc = ws[c];
        const float inv_wp1 = frcp(wpc + 1.0f);
        const int ibase = (b * Cv + c) * (Hv * Wv);
        for (int idx = t; idx < NTILE; idx += 128) {
            const int r  = idx / IW;
            const int cc = idx - r * IW;
            const int h  = h_base + r;
            const int w  = w_base + cc;
            float gxn = 0.f, cgxn = 0.f;
            if ((unsigned)h < (unsigned)Hv && (unsigned)w < (unsigned)Wv) {
                const int p = ibase + h * Wv + w;
                const float dv = d[p], cdv = cd[p], sv = s[p];
                const float gxv = gx[p], cgxv = cgx[p];
                const bool mLb = (w != Wv - 1);
                const bool mRb = (w != 0);
                const float dL = mLb ? dv : 0.f, cdL = mLb ? cdv : 0.f, sL = mLb ? sv : 0.f;
                const float dR = mRb ? dv : 0.f, cdR = mRb ? cdv : 0.f, sR = mRb ? sv : 0.f;
                const float cgx_ds = sv * sL * sR * cdL * cdR;
                const float height = (cdL * dL + cdR * dR) * frcp(cdL + cdR + EPSF);
                const float gx_ds  = (dR - dL) * 0.5f * frcp(height + EPSF);
                const float a = wpc * cgxv;
                gxn  = (a * gxv + cgx_ds * gx_ds) * frcp(a + cgx_ds + EPSF);
                cgxn = (a + cgx_ds) * inv_wp1;
            }
            lgx[r][cc]  = gxn;
            lcgx[r][cc] = cgxn;
        }
        __syncthreads();
        const int spb = ((b * Cv + c) * 9 * HOv + ho) * WOv + wo;
        float nom = 0.f, den = 0.f;
#pragma unroll
        for (int k = 0; k < 9; ++k) {
            const int ki = k / 3;
            const int kj = k - ki * 3;
            const float gxr  = lgx[2 * ho_l + ki][2 * wo_l + kj];
            const float cgxr = lcgx[2 * ho_l + ki][2 * wo_l + kj];
            const float spv  = sprod[spb + k * NPIX];
            const float cp   = cgxr * spv * sw_t[c * 9 + k];
            den += cp;
            nom = fmaf(cp, gxr, nom);
        }
        const float gx_sp  = nom * frcp(den + EPSF);
        const float cgx_sp = den * inv_sumsw;
        const float t1 = cgx_sp * gx_sp;
#pragma unroll
        for (int o = 0; o < Ov; ++o) {
            const float w_ = cw_t[o * Cv + c];
            nom2[o] = fmaf(t1, w_, nom2[o]);
            den2[o] = fmaf(cgx_sp, w_, den2[o]);
        }
        __syncthreads();
    }
#pragma unroll
    for (int o = 0; o < Ov; ++o) {
        const int p = ((b * Ov + o) * HOv + ho) * WOv + wo;
        const float dn = den2[o];
        const float g  = nom2[o] * frcp(dn + EPSF) + bias[o];
        out[p]            = g * 2.0f;
        out[HALF_OUT + p] = dn * inv_sumcw * 0.25f;
    }
}

extern "C" void kernel_launch(void* const* d_in, const int* in_sizes, int n_in,
                              void* d_out, int out_size, void* d_ws, size_t ws_size,
                              hipStream_t stream) {
    const float* d_ptr    = (const float*)d_in[0];
    const float* cd_ptr   = (const float*)d_in[1];
    const float* s_ptr    = (const float*)d_in[2];
    // d_in[3] = cs : unused by the reference
    const float* gx_ptr   = (const float*)d_in[4];
    const float* cgx_ptr  = (const float*)d_in[5];
    const float* sp_ptr   = (const float*)d_in[6];
    const float* wp_ptr   = (const float*)d_in[7];
    const float* sw_ptr   = (const float*)d_in[8];
    const float* cw_ptr   = (const float*)d_in[9];
    const float* bias_ptr = (const float*)d_in[10];
    float* out = (float*)d_out;
    float* ws  = (float*)d_ws;

    prep_kernel<<<1, 256, 0, stream>>>(wp_ptr, sw_ptr, cw_ptr, ws);

    if (ws_size >= WS_NEEDED) {
        float2* buf = (float2*)(ws + WS_BUF_OFF);
        dim3 g1(HOv / 4, Bv * Cv, 1);            // 32 x 128 = 4096 blocks
        k1_spatial<<<g1, 256, 0, stream>>>(d_ptr, cd_ptr, s_ptr, gx_ptr, cgx_ptr,
                                           sp_ptr, ws, buf);
        dim3 g2((Bv * NPIX) / 256, 2, 1);        // 256 x 2 blocks
        k2_channel<<<g2, 256, 0, stream>>>(buf, ws, bias_ptr, out);
    } else {
        dim3 grid(WOv / TW, HOv / TH, Bv);
        main_kernel<<<grid, 128, 0, stream>>>(d_ptr, cd_ptr, s_ptr, gx_ptr, cgx_ptr,
                                              sp_ptr, bias_ptr, ws, out);
    }
}